// Round 9
// baseline (558.618 us; speedup 1.0000x reference)
//
#include <hip/hip_runtime.h>

// GCNConv via CSR gather (atomic-free accumulation) + fused register transform.
// out = A_norm @ emb[x] @ W^T + b, A_norm = sym-normalized adjacency w/ self loops.
// N=100000, D=64, E=1200000. fp32 throughout.

#define N_NODES 100000
#define EDIM    64
#define N_EDGES 1200000
#define NB_SCAN ((N_NODES + 255) / 256)   // 391 scan blocks

__global__ void k_zero(int* __restrict__ cnt) {
    int i = blockIdx.x * blockDim.x + threadIdx.x;
    if (i < N_NODES) cnt[i] = 0;
}

__global__ void k_count(const int* __restrict__ dst, int* __restrict__ cnt) {
    int e = blockIdx.x * blockDim.x + threadIdx.x;
    if (e < N_EDGES) atomicAdd(&cnt[dst[e]], 1);
}

// per-block exclusive scan (256 elems) -> pre[], block total -> bsum[]
__global__ __launch_bounds__(256) void k_scan1(const int* __restrict__ cnt,
                                               int* __restrict__ pre,
                                               int* __restrict__ bsum) {
    __shared__ int s[256];
    const int tid = threadIdx.x;
    const int i = blockIdx.x * 256 + tid;
    int v = (i < N_NODES) ? cnt[i] : 0;
    s[tid] = v;
    __syncthreads();
#pragma unroll
    for (int off = 1; off < 256; off <<= 1) {
        int t = (tid >= off) ? s[tid - off] : 0;
        __syncthreads();
        s[tid] += t;
        __syncthreads();
    }
    if (i < N_NODES) pre[i] = s[tid] - v;       // exclusive
    if (tid == 255) bsum[blockIdx.x] = s[255];  // inclusive block total
}

// single-block exclusive scan of the 391 block sums (padded to 512)
__global__ __launch_bounds__(512) void k_scan2(int* __restrict__ bsum) {
    __shared__ int s[512];
    const int tid = threadIdx.x;
    int v = (tid < NB_SCAN) ? bsum[tid] : 0;
    s[tid] = v;
    __syncthreads();
#pragma unroll
    for (int off = 1; off < 512; off <<= 1) {
        int t = (tid >= off) ? s[tid - off] : 0;
        __syncthreads();
        s[tid] += t;
        __syncthreads();
    }
    if (tid < NB_SCAN) bsum[tid] = s[tid] - v;  // exclusive
}

// ptr = pre + block offset; wptr = ptr (fill cursor); dinv = rsqrt(cnt+1)
__global__ void k_scan3(const int* __restrict__ cnt, const int* __restrict__ pre,
                        const int* __restrict__ bsum, int* __restrict__ ptr,
                        int* __restrict__ wptr, float* __restrict__ dinv) {
    int i = blockIdx.x * blockDim.x + threadIdx.x;
    if (i < N_NODES) {
        int p = pre[i] + bsum[i >> 8];
        ptr[i] = p;
        wptr[i] = p;
        dinv[i] = rsqrtf((float)(cnt[i] + 1));
    }
}

// csr_src[slot in dst bucket] = src  (after this, wptr[i] == end of bucket i)
__global__ void k_fill(const int* __restrict__ src, const int* __restrict__ dst,
                       int* __restrict__ wptr, int* __restrict__ csr_src) {
    int e = blockIdx.x * blockDim.x + threadIdx.x;
    if (e < N_EDGES) {
        int pos = atomicAdd(&wptr[dst[e]], 1);
        csr_src[pos] = src[e];
    }
}

// One wave per node. Lane j holds agg[j]; in-register transform via readlane.
__global__ __launch_bounds__(256) void k_fused(const int* __restrict__ x,
                                               const int* __restrict__ ptr,
                                               const int* __restrict__ wptr,
                                               const int* __restrict__ csr_src,
                                               const float* __restrict__ dinv,
                                               const float* __restrict__ emb,
                                               const float* __restrict__ W,
                                               const float* __restrict__ b,
                                               float* __restrict__ out) {
    const int tid = threadIdx.x;
    const int j = tid & 63;
    const int node = blockIdx.x * 4 + (tid >> 6);

    // per-lane W row j (64 floats = 16 float4 VGPRs); 16 KB table -> L1-resident
    float4 w16[16];
#pragma unroll
    for (int c = 0; c < 16; ++c)
        w16[c] = *reinterpret_cast<const float4*>(&W[j * EDIM + c * 4]);
    const float bj = b[j];

    if (node >= N_NODES) return;

    const float di = dinv[node];
    const int xi = x[node];
    float acc = di * di * emb[xi * EDIM + j];     // self-loop term

    const int k0 = ptr[node];
    const int k1 = wptr[node];                    // == bucket end after k_fill
    for (int k = k0; k < k1; ++k) {
        int s = csr_src[k];                       // wave-uniform broadcast load
        float nrm = dinv[s] * di;
        int xs = x[s];
        acc = fmaf(nrm, emb[xs * EDIM + j], acc); // coalesced 256B gather
    }

    // out[node][j] = b[j] + sum_k W[j][k] * agg[k]; agg[k] via readlane (SALU)
    float o = bj;
#pragma unroll
    for (int k = 0; k < 64; ++k) {
        float a = __int_as_float(__builtin_amdgcn_readlane(__float_as_int(acc), k));
        float4 q = w16[k >> 2];
        float wv = ((k & 3) == 0) ? q.x : ((k & 3) == 1) ? q.y : ((k & 3) == 2) ? q.z : q.w;
        o = fmaf(a, wv, o);
    }
    out[node * EDIM + j] = o;
}

extern "C" void kernel_launch(void* const* d_in, const int* in_sizes, int n_in,
                              void* d_out, int out_size, void* d_ws, size_t ws_size,
                              hipStream_t stream) {
    const int*   x   = (const int*)d_in[0];
    const int*   ei  = (const int*)d_in[1];   // [2,E]: src = ei[0:E], dst = ei[E:2E]
    const float* emb = (const float*)d_in[2];
    const float* W   = (const float*)d_in[3];
    const float* b   = (const float*)d_in[4];
    float* out = (float*)d_out;

    const int* src = ei;
    const int* dst = ei + N_EDGES;

    // workspace layout (ints/floats, 4B each): ~6.8 MB total (ws proved >=26MB in R2)
    int*   cnt     = (int*)d_ws;
    int*   pre     = cnt + N_NODES;
    int*   ptr     = pre + N_NODES;
    int*   wptr    = ptr + N_NODES;
    int*   bsum    = wptr + N_NODES;           // 512 slots
    float* dinv    = (float*)(bsum + 512);
    int*   csr_src = (int*)(dinv + N_NODES);   // E ints

    k_zero <<<(N_NODES + 255) / 256, 256, 0, stream>>>(cnt);
    k_count<<<(N_EDGES + 255) / 256, 256, 0, stream>>>(dst, cnt);
    k_scan1<<<NB_SCAN, 256, 0, stream>>>(cnt, pre, bsum);
    k_scan2<<<1, 512, 0, stream>>>(bsum);
    k_scan3<<<(N_NODES + 255) / 256, 256, 0, stream>>>(cnt, pre, bsum, ptr, wptr, dinv);
    k_fill <<<(N_EDGES + 255) / 256, 256, 0, stream>>>(src, dst, wptr, csr_src);
    k_fused<<<(N_NODES + 3) / 4, 256, 0, stream>>>(x, ptr, wptr, csr_src, dinv, emb, W, b, out);
}

// Round 10
// 437.188 us; speedup vs baseline: 1.2778x; 1.2778x over previous
//
#include <hip/hip_runtime.h>

// GCNConv via CSR gather + latency-tolerant batched edge walk.
// out = A_norm @ emb[x] @ W^T + b. N=100000, D=64, E=1200000. fp32.

#define N_NODES 100000
#define EDIM    64
#define N_EDGES 1200000
#define NB_SCAN ((N_NODES + 255) / 256)   // 391 scan blocks

__global__ void k_zero(int* __restrict__ cnt) {
    int i = blockIdx.x * blockDim.x + threadIdx.x;
    if (i < N_NODES) cnt[i] = 0;
}

__global__ void k_count(const int* __restrict__ dst, int* __restrict__ cnt) {
    int e = blockIdx.x * blockDim.x + threadIdx.x;
    if (e < N_EDGES) atomicAdd(&cnt[dst[e]], 1);
}

__global__ __launch_bounds__(256) void k_scan1(const int* __restrict__ cnt,
                                               int* __restrict__ pre,
                                               int* __restrict__ bsum) {
    __shared__ int s[256];
    const int tid = threadIdx.x;
    const int i = blockIdx.x * 256 + tid;
    int v = (i < N_NODES) ? cnt[i] : 0;
    s[tid] = v;
    __syncthreads();
#pragma unroll
    for (int off = 1; off < 256; off <<= 1) {
        int t = (tid >= off) ? s[tid - off] : 0;
        __syncthreads();
        s[tid] += t;
        __syncthreads();
    }
    if (i < N_NODES) pre[i] = s[tid] - v;
    if (tid == 255) bsum[blockIdx.x] = s[255];
}

__global__ __launch_bounds__(512) void k_scan2(int* __restrict__ bsum) {
    __shared__ int s[512];
    const int tid = threadIdx.x;
    int v = (tid < NB_SCAN) ? bsum[tid] : 0;
    s[tid] = v;
    __syncthreads();
#pragma unroll
    for (int off = 1; off < 512; off <<= 1) {
        int t = (tid >= off) ? s[tid - off] : 0;
        __syncthreads();
        s[tid] += t;
        __syncthreads();
    }
    if (tid < NB_SCAN) bsum[tid] = s[tid] - v;
}

__global__ void k_scan3(const int* __restrict__ cnt, const int* __restrict__ pre,
                        const int* __restrict__ bsum, int* __restrict__ ptr,
                        int* __restrict__ wptr, float* __restrict__ dinv) {
    int i = blockIdx.x * blockDim.x + threadIdx.x;
    if (i < N_NODES) {
        int p = pre[i] + bsum[i >> 8];
        ptr[i] = p;
        wptr[i] = p;
        dinv[i] = rsqrtf((float)(cnt[i] + 1));
    }
}

__global__ void k_fill(const int* __restrict__ src, const int* __restrict__ dst,
                       int* __restrict__ wptr, int* __restrict__ csr_src) {
    int e = blockIdx.x * blockDim.x + threadIdx.x;
    if (e < N_EDGES) {
        int pos = atomicAdd(&wptr[dst[e]], 1);
        csr_src[pos] = src[e];
    }
}

// One wave per node. Chunked edge walk: 64 edges' metadata loaded lane-parallel,
// inner loop keeps 8 independent emb-row gathers in flight (addresses via shuffle,
// no memory op on the address path). Tail masked with zero weight.
__global__ __launch_bounds__(256) void k_fused(const int* __restrict__ x,
                                               const int* __restrict__ ptr,
                                               const int* __restrict__ wptr,
                                               const int* __restrict__ csr_src,
                                               const float* __restrict__ dinv,
                                               const float* __restrict__ emb,
                                               const float* __restrict__ W,
                                               const float* __restrict__ b,
                                               float* __restrict__ out) {
    const int tid = threadIdx.x;
    const int j = tid & 63;
    const int node = blockIdx.x * 4 + (tid >> 6);   // exact: 25000*4 == N_NODES

    // per-lane W row j (64 floats = 16 float4 VGPRs)
    float4 w16[16];
#pragma unroll
    for (int c = 0; c < 16; ++c)
        w16[c] = *reinterpret_cast<const float4*>(&W[j * EDIM + c * 4]);
    const float bj = b[j];

    const float di = dinv[node];
    float acc = di * di * emb[x[node] * EDIM + j];  // self-loop term

    const int k0  = ptr[node];
    const int deg = wptr[node] - k0;

    for (int base = 0; base < deg; base += 64) {
        const int cc = min(64, deg - base);
        // lane-parallel metadata: 3 independent gathers for up to 64 edges
        int s = 0;
        if (j < cc) s = csr_src[k0 + base + j];
        int   xs = x[s];
        float wv = dinv[s];

        for (int t = 0; t < cc; t += 8) {
            int   a[8]; float n[8]; float v[8];
#pragma unroll
            for (int u = 0; u < 8; ++u) {
                int idx  = t + u;
                int lane = (idx < cc) ? idx : 0;
                a[u] = __shfl(xs, lane);
                float nn = __shfl(wv, lane) * di;
                n[u] = (idx < cc) ? nn : 0.f;
            }
#pragma unroll
            for (int u = 0; u < 8; ++u) v[u] = emb[a[u] * EDIM + j];  // 8 in flight
#pragma unroll
            for (int u = 0; u < 8; ++u) acc = fmaf(n[u], v[u], acc);
        }
    }

    // out[node][j] = b[j] + sum_k W[j][k] * agg[k]; agg[k] via readlane
    float o = bj;
#pragma unroll
    for (int k = 0; k < 64; ++k) {
        float a = __int_as_float(__builtin_amdgcn_readlane(__float_as_int(acc), k));
        float4 q = w16[k >> 2];
        float wvv = ((k & 3) == 0) ? q.x : ((k & 3) == 1) ? q.y : ((k & 3) == 2) ? q.z : q.w;
        o = fmaf(a, wvv, o);
    }
    out[node * EDIM + j] = o;
}

extern "C" void kernel_launch(void* const* d_in, const int* in_sizes, int n_in,
                              void* d_out, int out_size, void* d_ws, size_t ws_size,
                              hipStream_t stream) {
    const int*   x   = (const int*)d_in[0];
    const int*   ei  = (const int*)d_in[1];   // [2,E]: src = ei[0:E], dst = ei[E:2E]
    const float* emb = (const float*)d_in[2];
    const float* W   = (const float*)d_in[3];
    const float* b   = (const float*)d_in[4];
    float* out = (float*)d_out;

    const int* src = ei;
    const int* dst = ei + N_EDGES;

    int*   cnt     = (int*)d_ws;
    int*   pre     = cnt + N_NODES;
    int*   ptr     = pre + N_NODES;
    int*   wptr    = ptr + N_NODES;
    int*   bsum    = wptr + N_NODES;           // 512 slots
    float* dinv    = (float*)(bsum + 512);
    int*   csr_src = (int*)(dinv + N_NODES);   // E ints

    k_zero <<<(N_NODES + 255) / 256, 256, 0, stream>>>(cnt);
    k_count<<<(N_EDGES + 255) / 256, 256, 0, stream>>>(dst, cnt);
    k_scan1<<<NB_SCAN, 256, 0, stream>>>(cnt, pre, bsum);
    k_scan2<<<1, 512, 0, stream>>>(bsum);
    k_scan3<<<(N_NODES + 255) / 256, 256, 0, stream>>>(cnt, pre, bsum, ptr, wptr, dinv);
    k_fill <<<(N_EDGES + 255) / 256, 256, 0, stream>>>(src, dst, wptr, csr_src);
    k_fused<<<N_NODES / 4, 256, 0, stream>>>(x, ptr, wptr, csr_src, dinv, emb, W, b, out);
}

// Round 11
// 408.457 us; speedup vs baseline: 1.3676x; 1.0703x over previous
//
#include <hip/hip_runtime.h>
#include <hip/hip_fp16.h>

// GCNConv: CSR + edge payload (xs, norm) + fp16 emb staging + pipelined gather.
// out = A_norm @ emb[x] @ W^T + b. N=100000, D=64, E=1200000. fp32 I/O.

#define N_NODES 100000
#define EDIM    64
#define N_EDGES 1200000
#define NB_SCAN ((N_NODES + 255) / 256)   // 391 scan blocks

__global__ void k_zero(int* __restrict__ cnt) {
    int i = blockIdx.x * blockDim.x + threadIdx.x;
    if (i < N_NODES) cnt[i] = 0;
}

// emb (fp32) -> emb2 (fp16), 4 elems/thread
__global__ void k_cvt(const float* __restrict__ emb, __half* __restrict__ emb2) {
    int i = blockIdx.x * blockDim.x + threadIdx.x;
    if (i < N_NODES * EDIM / 4) {
        float4 v = reinterpret_cast<const float4*>(emb)[i];
        ushort4 o;
        o.x = __half_as_ushort(__float2half(v.x));
        o.y = __half_as_ushort(__float2half(v.y));
        o.z = __half_as_ushort(__float2half(v.z));
        o.w = __half_as_ushort(__float2half(v.w));
        reinterpret_cast<ushort4*>(emb2)[i] = o;
    }
}

__global__ void k_count(const int* __restrict__ dst, int* __restrict__ cnt) {
    int e = blockIdx.x * blockDim.x + threadIdx.x;
    if (e < N_EDGES) atomicAdd(&cnt[dst[e]], 1);
}

__global__ __launch_bounds__(256) void k_scan1(const int* __restrict__ cnt,
                                               int* __restrict__ pre,
                                               int* __restrict__ bsum) {
    __shared__ int s[256];
    const int tid = threadIdx.x;
    const int i = blockIdx.x * 256 + tid;
    int v = (i < N_NODES) ? cnt[i] : 0;
    s[tid] = v;
    __syncthreads();
#pragma unroll
    for (int off = 1; off < 256; off <<= 1) {
        int t = (tid >= off) ? s[tid - off] : 0;
        __syncthreads();
        s[tid] += t;
        __syncthreads();
    }
    if (i < N_NODES) pre[i] = s[tid] - v;
    if (tid == 255) bsum[blockIdx.x] = s[255];
}

__global__ __launch_bounds__(512) void k_scan2(int* __restrict__ bsum) {
    __shared__ int s[512];
    const int tid = threadIdx.x;
    int v = (tid < NB_SCAN) ? bsum[tid] : 0;
    s[tid] = v;
    __syncthreads();
#pragma unroll
    for (int off = 1; off < 512; off <<= 1) {
        int t = (tid >= off) ? s[tid - off] : 0;
        __syncthreads();
        s[tid] += t;
        __syncthreads();
    }
    if (tid < NB_SCAN) bsum[tid] = s[tid] - v;
}

__global__ void k_scan3(const int* __restrict__ cnt, const int* __restrict__ pre,
                        const int* __restrict__ bsum, int* __restrict__ ptr,
                        int* __restrict__ wptr, float* __restrict__ dinv) {
    int i = blockIdx.x * blockDim.x + threadIdx.x;
    if (i < N_NODES) {
        int p = pre[i] + bsum[i >> 8];
        ptr[i] = p;
        wptr[i] = p;
        dinv[i] = rsqrtf((float)(cnt[i] + 1));
    }
}

// payload[slot] = { x[src], dinv[src]*dinv[dst] } — fused gather into the bin pass
__global__ void k_fill(const int* __restrict__ src, const int* __restrict__ dst,
                       const int* __restrict__ x, const float* __restrict__ dinv,
                       int* __restrict__ wptr, int2* __restrict__ pay) {
    int e = blockIdx.x * blockDim.x + threadIdx.x;
    if (e < N_EDGES) {
        int s = src[e];
        int d = dst[e];
        int pos = atomicAdd(&wptr[d], 1);
        pay[pos] = make_int2(x[s], __float_as_int(dinv[s] * dinv[d]));
    }
}

// One wave per node; chunk of 64 payloads loaded coalesced; inner loop keeps
// 8 independent fp16 row-gathers in flight; uniform readlane for metadata.
__global__ __launch_bounds__(256) void k_fused(const int* __restrict__ x,
                                               const int* __restrict__ ptr,
                                               const int* __restrict__ wptr,
                                               const int2* __restrict__ pay,
                                               const float* __restrict__ dinv,
                                               const __half* __restrict__ emb2,
                                               const float* __restrict__ W,
                                               const float* __restrict__ b,
                                               float* __restrict__ out) {
    const int tid = threadIdx.x;
    const int j = tid & 63;
    const int node = blockIdx.x * 4 + (tid >> 6);   // exact: 25000*4 == N_NODES

    float4 w16[16];
#pragma unroll
    for (int c = 0; c < 16; ++c)
        w16[c] = *reinterpret_cast<const float4*>(&W[j * EDIM + c * 4]);
    const float bj = b[j];

    const float di = dinv[node];
    float acc = di * di * __half2float(emb2[x[node] * EDIM + j]);  // self loop

    const int k0  = ptr[node];
    const int deg = wptr[node] - k0;

    for (int base = 0; base < deg; base += 64) {
        const int cc = min(64, deg - base);
        int2 pv = make_int2(0, 0);
        if (j < cc) pv = pay[k0 + base + j];        // one coalesced 8B load

        for (int t = 0; t < cc; t += 8) {
            int a[8]; float n[8]; float v[8];
#pragma unroll
            for (int u = 0; u < 8; ++u) {
                int idx  = t + u;                    // wave-uniform
                int lane = (idx < cc) ? idx : 0;
                a[u] = __builtin_amdgcn_readlane(pv.x, lane);
                float nn = __int_as_float(__builtin_amdgcn_readlane(pv.y, lane));
                n[u] = (idx < cc) ? nn : 0.f;        // nrm already includes di
            }
#pragma unroll
            for (int u = 0; u < 8; ++u) v[u] = __half2float(emb2[a[u] * EDIM + j]);
#pragma unroll
            for (int u = 0; u < 8; ++u) acc = fmaf(n[u], v[u], acc);
        }
    }

    float o = bj;
#pragma unroll
    for (int k = 0; k < 64; ++k) {
        float a = __int_as_float(__builtin_amdgcn_readlane(__float_as_int(acc), k));
        float4 q = w16[k >> 2];
        float wv = ((k & 3) == 0) ? q.x : ((k & 3) == 1) ? q.y : ((k & 3) == 2) ? q.z : q.w;
        o = fmaf(a, wv, o);
    }
    out[node * EDIM + j] = o;
}

extern "C" void kernel_launch(void* const* d_in, const int* in_sizes, int n_in,
                              void* d_out, int out_size, void* d_ws, size_t ws_size,
                              hipStream_t stream) {
    const int*   x   = (const int*)d_in[0];
    const int*   ei  = (const int*)d_in[1];   // [2,E]: src = ei[0:E], dst = ei[E:2E]
    const float* emb = (const float*)d_in[2];
    const float* W   = (const float*)d_in[3];
    const float* b   = (const float*)d_in[4];
    float* out = (float*)d_out;

    const int* src = ei;
    const int* dst = ei + N_EDGES;

    // ws: 500512 ints (2.0MB) | pay int2[E] (9.6MB) | emb2 half[N*64] (12.8MB) = 24.4MB
    int*    cnt  = (int*)d_ws;
    int*    pre  = cnt + N_NODES;
    int*    ptr  = pre + N_NODES;
    int*    wptr = ptr + N_NODES;
    int*    bsum = wptr + N_NODES;            // 512 slots
    float*  dinv = (float*)(bsum + 512);
    int2*   pay  = (int2*)(dinv + N_NODES);   // 8B-aligned (offset 2002048)
    __half* emb2 = (__half*)(pay + N_EDGES);

    k_zero <<<(N_NODES + 255) / 256, 256, 0, stream>>>(cnt);
    k_cvt  <<<(N_NODES * EDIM / 4 + 255) / 256, 256, 0, stream>>>(emb, emb2);
    k_count<<<(N_EDGES + 255) / 256, 256, 0, stream>>>(dst, cnt);
    k_scan1<<<NB_SCAN, 256, 0, stream>>>(cnt, pre, bsum);
    k_scan2<<<1, 512, 0, stream>>>(bsum);
    k_scan3<<<(N_NODES + 255) / 256, 256, 0, stream>>>(cnt, pre, bsum, ptr, wptr, dinv);
    k_fill <<<(N_EDGES + 255) / 256, 256, 0, stream>>>(src, dst, x, dinv, wptr, pay);
    k_fused<<<N_NODES / 4, 256, 0, stream>>>(x, ptr, wptr, pay, dinv, emb2, W, b, out);
}

// Round 18
// 264.456 us; speedup vs baseline: 2.1123x; 1.5445x over previous
//
#include <hip/hip_runtime.h>
#include <hip/hip_fp16.h>

// GCNConv: CSR + edge payload + fp16 emb + 16-lane-group aggregation + dense xform.
// out = A_norm @ emb[x] @ W^T + b. N=100000, D=64, E=1200000. fp32 I/O.

#define N_NODES 100000
#define EDIM    64
#define N_EDGES 1200000
#define NB_SCAN ((N_NODES + 255) / 256)   // 391 scan blocks

__global__ void k_zero(int* __restrict__ cnt) {
    int i = blockIdx.x * blockDim.x + threadIdx.x;
    if (i < N_NODES) cnt[i] = 0;
}

// fused: emb fp32->fp16 (i < N*64/4) and degree count (i < E)
__global__ void k_prep(const float* __restrict__ emb, __half* __restrict__ emb2,
                       const int* __restrict__ dst, int* __restrict__ cnt) {
    int i = blockIdx.x * blockDim.x + threadIdx.x;
    if (i < N_NODES * EDIM / 4) {
        float4 v = reinterpret_cast<const float4*>(emb)[i];
        ushort4 o;
        o.x = __half_as_ushort(__float2half(v.x));
        o.y = __half_as_ushort(__float2half(v.y));
        o.z = __half_as_ushort(__float2half(v.z));
        o.w = __half_as_ushort(__float2half(v.w));
        reinterpret_cast<ushort4*>(emb2)[i] = o;
    }
    if (i < N_EDGES) atomicAdd(&cnt[dst[i]], 1);
}

__global__ __launch_bounds__(256) void k_scan1(const int* __restrict__ cnt,
                                               int* __restrict__ pre,
                                               int* __restrict__ bsum) {
    __shared__ int s[256];
    const int tid = threadIdx.x;
    const int i = blockIdx.x * 256 + tid;
    int v = (i < N_NODES) ? cnt[i] : 0;
    s[tid] = v;
    __syncthreads();
#pragma unroll
    for (int off = 1; off < 256; off <<= 1) {
        int t = (tid >= off) ? s[tid - off] : 0;
        __syncthreads();
        s[tid] += t;
        __syncthreads();
    }
    if (i < N_NODES) pre[i] = s[tid] - v;
    if (tid == 255) bsum[blockIdx.x] = s[255];
}

__global__ __launch_bounds__(512) void k_scan2(int* __restrict__ bsum) {
    __shared__ int s[512];
    const int tid = threadIdx.x;
    int v = (tid < NB_SCAN) ? bsum[tid] : 0;
    s[tid] = v;
    __syncthreads();
#pragma unroll
    for (int off = 1; off < 512; off <<= 1) {
        int t = (tid >= off) ? s[tid - off] : 0;
        __syncthreads();
        s[tid] += t;
        __syncthreads();
    }
    if (tid < NB_SCAN) bsum[tid] = s[tid] - v;
}

__global__ void k_scan3(const int* __restrict__ cnt, const int* __restrict__ pre,
                        const int* __restrict__ bsum, int* __restrict__ ptr,
                        int* __restrict__ wptr, float* __restrict__ dinv) {
    int i = blockIdx.x * blockDim.x + threadIdx.x;
    if (i < N_NODES) {
        int p = pre[i] + bsum[i >> 8];
        ptr[i] = p;
        wptr[i] = p;
        dinv[i] = rsqrtf((float)(cnt[i] + 1));
    }
}

// payload[slot] = { x[src], dinv[src]*dinv[dst] }
__global__ void k_fill(const int* __restrict__ src, const int* __restrict__ dst,
                       const int* __restrict__ x, const float* __restrict__ dinv,
                       int* __restrict__ wptr, int2* __restrict__ pay) {
    int e = blockIdx.x * blockDim.x + threadIdx.x;
    if (e < N_EDGES) {
        int s = src[e];
        int d = dst[e];
        int pos = atomicAdd(&wptr[d], 1);
        pay[pos] = make_int2(x[s], __float_as_int(dinv[s] * dinv[d]));
    }
}

// 16 lanes per node (half4 per lane = 128B row). 16 groups/block, 4 streams/wave,
// 8-deep gather pipeline per group -> 32 outstanding loads per wave.
__global__ __launch_bounds__(256) void k_agg(const int* __restrict__ x,
                                             const int* __restrict__ ptr,
                                             const int* __restrict__ wptr,
                                             const int2* __restrict__ pay,
                                             const float* __restrict__ dinv,
                                             const __half* __restrict__ emb2,
                                             float* __restrict__ agg) {
    const int tid   = threadIdx.x;
    const int l     = tid & 15;                     // lane within group
    const int node  = blockIdx.x * 16 + (tid >> 4); // 6250*16 == N_NODES exact
    const int wl    = tid & 63;
    const int lbase = wl & ~15;                     // group's base lane in wave

    const float di = dinv[node];
    const float dd = di * di;
    const int   xi = x[node];

    uint2 sh = *reinterpret_cast<const uint2*>(&emb2[xi * EDIM + l * 4]);
    float2 f01 = __half22float2(*reinterpret_cast<const __half2*>(&sh.x));
    float2 f23 = __half22float2(*reinterpret_cast<const __half2*>(&sh.y));
    float4 acc = make_float4(dd * f01.x, dd * f01.y, dd * f23.x, dd * f23.y);

    const int k0  = ptr[node];
    const int deg = wptr[node] - k0;

    for (int base = 0; base < deg; base += 16) {
        const int cc = min(16, deg - base);
        int2 pv = make_int2(0, 0);
        if (l < cc) pv = pay[k0 + base + l];        // 16x8B coalesced

        for (int t = 0; t < cc; t += 8) {
            int a[8]; float n[8]; uint2 v[8];
#pragma unroll
            for (int u = 0; u < 8; ++u) {
                int idx = t + u;
                int sel = (idx < cc) ? idx : 0;
                a[u] = __shfl(pv.x, lbase + sel);
                float nn = __int_as_float(__shfl(pv.y, lbase + sel));
                n[u] = (idx < cc) ? nn : 0.f;
            }
#pragma unroll
            for (int u = 0; u < 8; ++u)             // 8 independent 128B row gathers
                v[u] = *reinterpret_cast<const uint2*>(&emb2[a[u] * EDIM + l * 4]);
#pragma unroll
            for (int u = 0; u < 8; ++u) {
                float2 g01 = __half22float2(*reinterpret_cast<const __half2*>(&v[u].x));
                float2 g23 = __half22float2(*reinterpret_cast<const __half2*>(&v[u].y));
                acc.x = fmaf(n[u], g01.x, acc.x);
                acc.y = fmaf(n[u], g01.y, acc.y);
                acc.z = fmaf(n[u], g23.x, acc.z);
                acc.w = fmaf(n[u], g23.y, acc.w);
            }
        }
    }
    *reinterpret_cast<float4*>(&agg[node * EDIM + l * 4]) = acc;
}

// dense: out[n][j] = b[j] + sum_k W[j][k] * agg[n][k]; in-place on d_out (agg==out).
// lane j owns W row j in regs; 4 split fma chains of 16.
__global__ __launch_bounds__(256) void k_xform(float* __restrict__ agg,
                                               const float* __restrict__ W,
                                               const float* __restrict__ b) {
    const int tid = threadIdx.x;
    const int j = tid & 63;
    const int wid = blockIdx.x * 4 + (tid >> 6);
    const int nw  = gridDim.x * 4;

    float4 w16[16];
#pragma unroll
    for (int c = 0; c < 16; ++c)
        w16[c] = *reinterpret_cast<const float4*>(&W[j * EDIM + c * 4]);
    const float bj = b[j];

    for (int n = wid; n < N_NODES; n += nw) {
        const float aj = agg[n * EDIM + j];         // coalesced row load
        float o0 = bj, o1 = 0.f, o2 = 0.f, o3 = 0.f;
#pragma unroll
        for (int k = 0; k < 16; ++k) {
            float a0 = __int_as_float(__builtin_amdgcn_readlane(__float_as_int(aj), k));
            float a1 = __int_as_float(__builtin_amdgcn_readlane(__float_as_int(aj), k + 16));
            float a2 = __int_as_float(__builtin_amdgcn_readlane(__float_as_int(aj), k + 32));
            float a3 = __int_as_float(__builtin_amdgcn_readlane(__float_as_int(aj), k + 48));
            float4 q0 = w16[k >> 2];
            float4 q1 = w16[(k + 16) >> 2];
            float4 q2 = w16[(k + 32) >> 2];
            float4 q3 = w16[(k + 48) >> 2];
            float w0 = ((k & 3) == 0) ? q0.x : ((k & 3) == 1) ? q0.y : ((k & 3) == 2) ? q0.z : q0.w;
            float w1 = ((k & 3) == 0) ? q1.x : ((k & 3) == 1) ? q1.y : ((k & 3) == 2) ? q1.z : q1.w;
            float w2 = ((k & 3) == 0) ? q2.x : ((k & 3) == 1) ? q2.y : ((k & 3) == 2) ? q2.z : q2.w;
            float w3 = ((k & 3) == 0) ? q3.x : ((k & 3) == 1) ? q3.y : ((k & 3) == 2) ? q3.z : q3.w;
            o0 = fmaf(a0, w0, o0);
            o1 = fmaf(a1, w1, o1);
            o2 = fmaf(a2, w2, o2);
            o3 = fmaf(a3, w3, o3);
        }
        agg[n * EDIM + j] = (o0 + o1) + (o2 + o3);
    }
}

extern "C" void kernel_launch(void* const* d_in, const int* in_sizes, int n_in,
                              void* d_out, int out_size, void* d_ws, size_t ws_size,
                              hipStream_t stream) {
    const int*   x   = (const int*)d_in[0];
    const int*   ei  = (const int*)d_in[1];   // [2,E]: src = ei[0:E], dst = ei[E:2E]
    const float* emb = (const float*)d_in[2];
    const float* W   = (const float*)d_in[3];
    const float* b   = (const float*)d_in[4];
    float* out = (float*)d_out;               // doubles as agg buffer

    const int* src = ei;
    const int* dst = ei + N_EDGES;

    // ws: 500512 ints (2.0MB) | pay int2[E] (9.6MB) | emb2 half[N*64] (12.8MB) = 24.4MB
    int*    cnt  = (int*)d_ws;
    int*    pre  = cnt + N_NODES;
    int*    ptr  = pre + N_NODES;
    int*    wptr = ptr + N_NODES;
    int*    bsum = wptr + N_NODES;            // 512 slots
    float*  dinv = (float*)(bsum + 512);
    int2*   pay  = (int2*)(dinv + N_NODES);   // 8B-aligned
    __half* emb2 = (__half*)(pay + N_EDGES);

    k_zero <<<(N_NODES + 255) / 256, 256, 0, stream>>>(cnt);
    k_prep <<<(N_NODES * EDIM / 4 + 255) / 256, 256, 0, stream>>>(emb, emb2, dst, cnt);
    k_scan1<<<NB_SCAN, 256, 0, stream>>>(cnt, pre, bsum);
    k_scan2<<<1, 512, 0, stream>>>(bsum);
    k_scan3<<<(N_NODES + 255) / 256, 256, 0, stream>>>(cnt, pre, bsum, ptr, wptr, dinv);
    k_fill <<<(N_EDGES + 255) / 256, 256, 0, stream>>>(src, dst, x, dinv, wptr, pay);
    k_agg  <<<N_NODES / 16, 256, 0, stream>>>(x, ptr, wptr, pay, dinv, emb2, out);
    k_xform<<<2048, 256, 0, stream>>>(out, W, b);
}